// Round 1
// baseline (367.910 us; speedup 1.0000x reference)
//
#include <hip/hip_runtime.h>
#include <hip/hip_fp16.h>

#define B_  8
#define D_  512
#define H_  512
#define L_  8192
#define O2_ 1024   // 2*H

typedef __attribute__((ext_vector_type(8))) short   bf16x8;
typedef __attribute__((ext_vector_type(4))) float   floatx4;
typedef __attribute__((ext_vector_type(8))) unsigned short ushort8_t;
typedef __attribute__((ext_vector_type(4))) unsigned short ushort4_t;

__device__ __forceinline__ unsigned short f2bf(float f) {
    union { float f; unsigned u; } x; x.f = f;
    unsigned u = x.u;
    u += 0x7FFFu + ((u >> 16) & 1u);   // round-to-nearest-even
    return (unsigned short)(u >> 16);
}

// ---------------- K0: reorder W rows (pair-interleave) + convert to bf16 ----
// Wr[2k]   = W[k], Wr[2k+1] = W[H+k]
__global__ __launch_bounds__(256) void prep_w(const float* __restrict__ W,
                                              unsigned short* __restrict__ Wr) {
    int idx  = blockIdx.x * 256 + threadIdx.x;   // 131072 threads, 4 elems each
    int flat = idx * 4;
    int o = flat >> 9;        // /512
    int d = flat & 511;
    int src_o = (o & 1) ? (H_ + (o >> 1)) : (o >> 1);
    float4 wv = *(const float4*)(W + (size_t)src_o * D_ + d);
    ushort4_t r;
    r.x = f2bf(wv.x); r.y = f2bf(wv.y); r.z = f2bf(wv.z); r.w = f2bf(wv.w);
    *(ushort4_t*)(Wr + (size_t)o * D_ + d) = r;
}

// ---------------- K1: x [B][D][L] fp32  ->  xT [B][L][D] bf16 ---------------
__global__ __launch_bounds__(256) void transpose_x(const float* __restrict__ x,
                                                   unsigned short* __restrict__ xT) {
    __shared__ float T[64][65];
    const int b  = blockIdx.z;
    const int d0 = blockIdx.y * 64;
    const int l0 = blockIdx.x * 64;
    const int tid = threadIdx.x;

    const int c  = tid & 15;       // float4 column within l
    const int r0 = tid >> 4;       // starting d-row
    const float* xp = x + ((size_t)b * D_ + d0) * L_ + l0;
    for (int rr = r0; rr < 64; rr += 16) {
        float4 vv = *(const float4*)(xp + (size_t)rr * L_ + c * 4);
        T[c * 4 + 0][rr] = vv.x;
        T[c * 4 + 1][rr] = vv.y;
        T[c * 4 + 2][rr] = vv.z;
        T[c * 4 + 3][rr] = vv.w;
    }
    __syncthreads();

    const int dc  = (tid & 7) * 8;  // d chunk (8 bf16 = 16B store)
    const int lr0 = tid >> 3;       // l row
    unsigned short* op = xT + ((size_t)b * L_ + l0) * D_ + d0;
    for (int lr = lr0; lr < 64; lr += 32) {
        ushort8_t o8;
        o8[0] = f2bf(T[lr][dc + 0]); o8[1] = f2bf(T[lr][dc + 1]);
        o8[2] = f2bf(T[lr][dc + 2]); o8[3] = f2bf(T[lr][dc + 3]);
        o8[4] = f2bf(T[lr][dc + 4]); o8[5] = f2bf(T[lr][dc + 5]);
        o8[6] = f2bf(T[lr][dc + 6]); o8[7] = f2bf(T[lr][dc + 7]);
        *(ushort8_t*)(op + (size_t)lr * D_ + dc) = o8;
    }
}

// ---------------- K2: hg = Wr @ xT^T  (bf16 MFMA, 128x128 tile, BK=64) ------
// Output hg [B][1024][L] fp16 (no bias — added in scan kernel).
__global__ __launch_bounds__(256) void gemm_hg(const unsigned short* __restrict__ Wr,
                                               const unsigned short* __restrict__ xT,
                                               __half* __restrict__ hg) {
    __shared__ unsigned short As[128][72];   // [o][d], +8 pad
    __shared__ unsigned short Bs[128][72];   // [l][d], +8 pad

    const int b  = blockIdx.z;
    const int o0 = blockIdx.y * 128;
    const int l0 = blockIdx.x * 128;
    const int tid  = threadIdx.x;
    const int lane = tid & 63;
    const int w    = tid >> 6;
    const int wm   = (w >> 1) * 64;
    const int wn   = (w & 1) * 64;
    const int lm   = lane & 15;
    const int quad = lane >> 4;

    floatx4 acc[4][4];
    for (int mi = 0; mi < 4; ++mi)
        for (int ni = 0; ni < 4; ++ni)
            acc[mi][ni] = (floatx4){0.f, 0.f, 0.f, 0.f};

    const int srow = tid >> 3;        // 0..31
    const int scol = (tid & 7) * 8;   // 0..56 step 8
    const unsigned short* Ab = Wr + (size_t)(o0 + srow) * D_ + scol;
    const unsigned short* Bb = xT + ((size_t)b * L_ + l0 + srow) * D_ + scol;

    for (int kk = 0; kk < 8; ++kk) {
        const int k0 = kk * 64;
        for (int p = 0; p < 4; ++p) {
            uint4 av = *(const uint4*)(Ab + (size_t)(p * 32) * D_ + k0);
            uint4 bv = *(const uint4*)(Bb + (size_t)(p * 32) * D_ + k0);
            *(uint4*)&As[srow + p * 32][scol] = av;
            *(uint4*)&Bs[srow + p * 32][scol] = bv;
        }
        __syncthreads();

        for (int ks = 0; ks < 2; ++ks) {
            const int koff = ks * 32 + quad * 8;
            bf16x8 af[4], bfv[4];
            for (int mi = 0; mi < 4; ++mi)
                af[mi] = *(const bf16x8*)&As[wm + mi * 16 + lm][koff];
            for (int ni = 0; ni < 4; ++ni)
                bfv[ni] = *(const bf16x8*)&Bs[wn + ni * 16 + lm][koff];
            for (int mi = 0; mi < 4; ++mi)
                for (int ni = 0; ni < 4; ++ni)
                    acc[mi][ni] = __builtin_amdgcn_mfma_f32_16x16x32_bf16(
                        af[mi], bfv[ni], acc[mi][ni], 0, 0, 0);
        }
        __syncthreads();
    }

    // epilogue: D[row=quad*4+r][col=lm] per 16x16 tile
    __half* hp = hg + ((size_t)b * O2_ + o0 + wm + quad * 4) * L_ + l0 + wn + lm;
    for (int mi = 0; mi < 4; ++mi)
        for (int ni = 0; ni < 4; ++ni)
            for (int r = 0; r < 4; ++r)
                hp[(size_t)(mi * 16 + r) * L_ + ni * 16] = __float2half(acc[mi][ni][r]);
}

// ---------------- K3: per-(b,k) chunked parallel scan -----------------------
__global__ __launch_bounds__(256) void scan_seq(const __half* __restrict__ hg,
                                                const float* __restrict__ bias,
                                                float* __restrict__ out) {
    __shared__ float sA[256];
    __shared__ float sB[256];
    const int bid = blockIdx.x;
    const int b = bid >> 9;
    const int k = bid & 511;
    const int t = threadIdx.x;

    const __half* hp = hg + ((size_t)b * O2_ + 2 * k) * L_ + t * 32;
    const __half* gp = hp + L_;
    const float bh = bias[k];
    const float bg = bias[H_ + k];

    union U { uint4 q; __half h[8]; };
    U hu[4], gu[4];
    const uint4* hq = (const uint4*)hp;
    const uint4* gq = (const uint4*)gp;
    for (int i = 0; i < 4; ++i) { hu[i].q = hq[i]; gu[i].q = gq[i]; }

    float c[32], v[32];
    float A = 1.f, Bv = 0.f;
    for (int i = 0; i < 32; ++i) {
        float hf = __half2float(hu[i >> 3].h[i & 7]) + bh;
        float gf = __half2float(gu[i >> 3].h[i & 7]) + bg;
        float e   = __expf(gf);
        float inv = 1.f / (1.f + e);
        float ci  = inv;        // sigmoid(-gate)
        float zi  = e * inv;    // sigmoid(gate)
        float gv  = (hf >= 0.f) ? (1.f + hf) : __expf(hf);
        float vi  = zi * gv;
        c[i] = ci; v[i] = vi;
        Bv = ci * Bv + vi;
        A *= ci;
    }

    sA[t] = A; sB[t] = Bv;
    __syncthreads();
    for (int off = 1; off < 256; off <<= 1) {
        float pA = 1.f, pB = 0.f;
        if (t >= off) { pA = sA[t - off]; pB = sB[t - off]; }
        __syncthreads();
        Bv = Bv + A * pB;
        A  = A * pA;
        sA[t] = A; sB[t] = Bv;
        __syncthreads();
    }
    float hr = (t > 0) ? sB[t - 1] : 0.f;

    float* op = out + ((size_t)b * H_ + k) * L_ + t * 32;
    for (int i = 0; i < 32; i += 4) {
        float4 o4;
        o4.x = hr = c[i + 0] * hr + v[i + 0];
        o4.y = hr = c[i + 1] * hr + v[i + 1];
        o4.z = hr = c[i + 2] * hr + v[i + 2];
        o4.w = hr = c[i + 3] * hr + v[i + 3];
        *(float4*)(op + i) = o4;
    }
}

// ---------------- fallback: fully fused naive (if ws too small) -------------
__global__ __launch_bounds__(256) void fused_naive(const float* __restrict__ x,
                                                   const float* __restrict__ W,
                                                   const float* __restrict__ bias,
                                                   float* __restrict__ out) {
    __shared__ float Wh[512];
    __shared__ float Wg[512];
    __shared__ float sA[256];
    __shared__ float sB[256];
    const int bid = blockIdx.x;
    const int b = bid >> 9;
    const int k = bid & 511;
    const int t = threadIdx.x;

    for (int i = t; i < 512; i += 256) {
        Wh[i] = W[(size_t)k * D_ + i];
        Wg[i] = W[(size_t)(H_ + k) * D_ + i];
    }
    const float bh = bias[k];
    const float bg = bias[H_ + k];
    __syncthreads();

    float Hc = 0.f;
    const float* xb = x + (size_t)b * D_ * L_;
    for (int ch = 0; ch < 32; ++ch) {
        const int l = ch * 256 + t;
        float ah = bh, ag = bg;
        for (int d = 0; d < 512; ++d) {
            float xv = xb[(size_t)d * L_ + l];
            ah += Wh[d] * xv;
            ag += Wg[d] * xv;
        }
        float e   = __expf(ag);
        float inv = 1.f / (1.f + e);
        float ci  = inv;
        float zi  = e * inv;
        float gv  = (ah >= 0.f) ? (1.f + ah) : __expf(ah);
        float vi  = zi * gv;

        float A = ci, Bv = vi;
        sA[t] = A; sB[t] = Bv;
        __syncthreads();
        for (int off = 1; off < 256; off <<= 1) {
            float pA = 1.f, pB = 0.f;
            if (t >= off) { pA = sA[t - off]; pB = sB[t - off]; }
            __syncthreads();
            Bv = Bv + A * pB;
            A  = A * pA;
            sA[t] = A; sB[t] = Bv;
            __syncthreads();
        }
        out[((size_t)b * H_ + k) * L_ + l] = A * Hc + Bv;
        float An = sA[255], Bn = sB[255];
        Hc = An * Hc + Bn;
        __syncthreads();
    }
}

extern "C" void kernel_launch(void* const* d_in, const int* in_sizes, int n_in,
                              void* d_out, int out_size, void* d_ws, size_t ws_size,
                              hipStream_t stream) {
    const float* x    = (const float*)d_in[0];
    const float* W    = (const float*)d_in[1];
    const float* bias = (const float*)d_in[2];
    float* out = (float*)d_out;

    const size_t xT_bytes = (size_t)B_ * L_ * D_ * 2;        //  67,108,864
    const size_t Wr_bytes = (size_t)O2_ * D_ * 2;            //   1,048,576
    const size_t hg_bytes = (size_t)B_ * O2_ * L_ * 2;       // 134,217,728
    const size_t need = xT_bytes + Wr_bytes + hg_bytes;      // ~202 MB

    if (ws_size >= need) {
        char* ws = (char*)d_ws;
        unsigned short* xT = (unsigned short*)ws;
        unsigned short* Wr = (unsigned short*)(ws + xT_bytes);
        __half*         hg = (__half*)(ws + xT_bytes + Wr_bytes);

        prep_w<<<512, 256, 0, stream>>>(W, Wr);
        transpose_x<<<dim3(L_ / 64, D_ / 64, B_), 256, 0, stream>>>(x, xT);
        gemm_hg<<<dim3(L_ / 128, O2_ / 128, B_), 256, 0, stream>>>(Wr, xT, hg);
        scan_seq<<<B_ * H_, 256, 0, stream>>>(hg, bias, out);
    } else {
        fused_naive<<<B_ * H_, 256, 0, stream>>>(x, W, bias, out);
    }
}

// Round 2
// 362.284 us; speedup vs baseline: 1.0155x; 1.0155x over previous
//
#include <hip/hip_runtime.h>
#include <hip/hip_fp16.h>

#define B_  8
#define D_  512
#define H_  512
#define L_  8192
#define O2_ 1024   // 2*H

typedef __attribute__((ext_vector_type(8))) short   bf16x8;
typedef __attribute__((ext_vector_type(4))) float   floatx4;
typedef __attribute__((ext_vector_type(8))) unsigned short ushort8_t;
typedef __attribute__((ext_vector_type(4))) unsigned short ushort4_t;

__device__ __forceinline__ unsigned short f2bf(float f) {
    union { float f; unsigned u; } x; x.f = f;
    unsigned u = x.u;
    u += 0x7FFFu + ((u >> 16) & 1u);   // round-to-nearest-even
    return (unsigned short)(u >> 16);
}

// async global->LDS, 16B per lane; LDS dest = wave-uniform base + lane*16
__device__ __forceinline__ void async_load16(const void* g, void* l) {
    __builtin_amdgcn_global_load_lds(
        (const __attribute__((address_space(1))) unsigned int*)g,
        (__attribute__((address_space(3))) unsigned int*)l,
        16, 0, 0);
}

// ---------------- K0: reorder W rows (pair-interleave) + convert to bf16 ----
// Wr[2k]   = W[k], Wr[2k+1] = W[H+k]
__global__ __launch_bounds__(256) void prep_w(const float* __restrict__ W,
                                              unsigned short* __restrict__ Wr) {
    int idx  = blockIdx.x * 256 + threadIdx.x;
    int flat = idx * 4;
    int o = flat >> 9;        // /512
    int d = flat & 511;
    int src_o = (o & 1) ? (H_ + (o >> 1)) : (o >> 1);
    float4 wv = *(const float4*)(W + (size_t)src_o * D_ + d);
    ushort4_t r;
    r.x = f2bf(wv.x); r.y = f2bf(wv.y); r.z = f2bf(wv.z); r.w = f2bf(wv.w);
    *(ushort4_t*)(Wr + (size_t)o * D_ + d) = r;
}

// ---------------- K1: x [B][D][L] fp32  ->  xT [B][L][D] bf16 ---------------
__global__ __launch_bounds__(256) void transpose_x(const float* __restrict__ x,
                                                   unsigned short* __restrict__ xT) {
    __shared__ float T[64][65];
    const int b  = blockIdx.z;
    const int d0 = blockIdx.y * 64;
    const int l0 = blockIdx.x * 64;
    const int tid = threadIdx.x;

    const int c  = tid & 15;       // float4 column within l
    const int r0 = tid >> 4;       // starting d-row
    const float* xp = x + ((size_t)b * D_ + d0) * L_ + l0;
    for (int rr = r0; rr < 64; rr += 16) {
        float4 vv = *(const float4*)(xp + (size_t)rr * L_ + c * 4);
        T[c * 4 + 0][rr] = vv.x;
        T[c * 4 + 1][rr] = vv.y;
        T[c * 4 + 2][rr] = vv.z;
        T[c * 4 + 3][rr] = vv.w;
    }
    __syncthreads();

    const int dc  = (tid & 7) * 8;  // d chunk (8 bf16 = 16B store)
    const int lr0 = tid >> 3;       // l row
    unsigned short* op = xT + ((size_t)b * L_ + l0) * D_ + d0;
    for (int lr = lr0; lr < 64; lr += 32) {
        ushort8_t o8;
        o8[0] = f2bf(T[lr][dc + 0]); o8[1] = f2bf(T[lr][dc + 1]);
        o8[2] = f2bf(T[lr][dc + 2]); o8[3] = f2bf(T[lr][dc + 3]);
        o8[4] = f2bf(T[lr][dc + 4]); o8[5] = f2bf(T[lr][dc + 5]);
        o8[6] = f2bf(T[lr][dc + 6]); o8[7] = f2bf(T[lr][dc + 7]);
        *(ushort8_t*)(op + (size_t)lr * D_ + dc) = o8;
    }
}

// ---------------- K2: hg = Wr @ xT^T  (m97-style: global_load_lds staging) --
// LDS layout UNPADDED [128][64]: required by global_load_lds lane-contiguity.
__global__ __launch_bounds__(256) void gemm_hg(const unsigned short* __restrict__ Wr,
                                               const unsigned short* __restrict__ xT,
                                               __half* __restrict__ hg) {
    __shared__ __align__(16) unsigned short As[128][64];   // 16 KB
    __shared__ __align__(16) unsigned short Bs[128][64];   // 16 KB

    const int b  = blockIdx.z;
    const int o0 = blockIdx.y * 128;
    const int l0 = blockIdx.x * 128;
    const int tid  = threadIdx.x;
    const int lane = tid & 63;
    const int w    = tid >> 6;
    const int wm   = (w >> 1) * 64;
    const int wn   = (w & 1) * 64;
    const int lm   = lane & 15;
    const int quad = lane >> 4;

    floatx4 acc[4][4];
    for (int mi = 0; mi < 4; ++mi)
        for (int ni = 0; ni < 4; ++ni)
            acc[mi][ni] = (floatx4){0.f, 0.f, 0.f, 0.f};

    // wave w stages rows [w*32, w*32+32); lane i -> row +(i>>3), col (i&7)*8
    const int srow = w * 32 + (lane >> 3);
    const int scol = (lane & 7) * 8;
    const unsigned short* Ag = Wr + (size_t)(o0 + srow) * D_ + scol;
    const unsigned short* Bg = xT + ((size_t)b * L_ + l0 + srow) * D_ + scol;

    for (int kk = 0; kk < 8; ++kk) {
        const int k0 = kk * 64;
        #pragma unroll
        for (int p = 0; p < 4; ++p) {
            async_load16(Ag + (size_t)(p * 8) * D_ + k0, &As[w * 32 + p * 8][0]);
            async_load16(Bg + (size_t)(p * 8) * D_ + k0, &Bs[w * 32 + p * 8][0]);
        }
        __syncthreads();   // drains vmcnt -> LDS visible

        #pragma unroll
        for (int ks = 0; ks < 2; ++ks) {
            const int koff = ks * 32 + quad * 8;
            bf16x8 af[4], bfv[4];
            #pragma unroll
            for (int mi = 0; mi < 4; ++mi)
                af[mi] = *(const bf16x8*)&As[wm + mi * 16 + lm][koff];
            #pragma unroll
            for (int ni = 0; ni < 4; ++ni)
                bfv[ni] = *(const bf16x8*)&Bs[wn + ni * 16 + lm][koff];
            #pragma unroll
            for (int mi = 0; mi < 4; ++mi)
                #pragma unroll
                for (int ni = 0; ni < 4; ++ni)
                    acc[mi][ni] = __builtin_amdgcn_mfma_f32_16x16x32_bf16(
                        af[mi], bfv[ni], acc[mi][ni], 0, 0, 0);
        }
        __syncthreads();
    }

    // epilogue: D[row=quad*4+r][col=lm] per 16x16 tile
    __half* hp = hg + ((size_t)b * O2_ + o0 + wm + quad * 4) * L_ + l0 + wn + lm;
    for (int mi = 0; mi < 4; ++mi)
        for (int ni = 0; ni < 4; ++ni)
            for (int r = 0; r < 4; ++r)
                hp[(size_t)(mi * 16 + r) * L_ + ni * 16] = __float2half(acc[mi][ni][r]);
}

// ---------------- K3: per-(b,k) chunked parallel scan, LDS-staged IO --------
__global__ __launch_bounds__(256, 3) void scan_seq(const __half* __restrict__ hg,
                                                   const float* __restrict__ bias,
                                                   float* __restrict__ out) {
    // sBuf: h chunks [256][20] uints (20 KB) + g chunks [256][20] (20 KB);
    // reused as out chunks [256][36] floats (36 KB) after the scan.
    __shared__ __align__(16) unsigned int sBuf[256 * 40];
    __shared__ float sA[256];
    __shared__ float sB[256];
    unsigned int* sH = sBuf;
    unsigned int* sG = sBuf + 256 * 20;

    const int bid = blockIdx.x;
    const int b = bid >> 9;
    const int k = bid & 511;
    const int t = threadIdx.x;

    const uint4* hq = (const uint4*)(hg + ((size_t)b * O2_ + 2 * k) * L_);
    const uint4* gq = hq + (L_ / 8);   // next row (gate), 1024 uint4 per row

    // cooperative, fully-coalesced load into padded-chunk LDS layout
    #pragma unroll
    for (int j = 0; j < 4; ++j) {
        int idx = t + 256 * j;               // uint4 index 0..1023
        uint4 hv = hq[idx];
        uint4 gv = gq[idx];
        int cc = idx >> 2, ss = idx & 3;     // chunk 16 uints, pad to 20
        *(uint4*)&sH[cc * 20 + ss * 4] = hv;
        *(uint4*)&sG[cc * 20 + ss * 4] = gv;
    }
    const float bh = bias[k];
    const float bg = bias[H_ + k];
    __syncthreads();

    float c[32], v[32];
    float A = 1.f, Bv = 0.f;
    #pragma unroll
    for (int j4 = 0; j4 < 4; ++j4) {
        uint4 hv = *(const uint4*)&sH[t * 20 + j4 * 4];
        uint4 gv = *(const uint4*)&sG[t * 20 + j4 * 4];
        unsigned hu[4] = {hv.x, hv.y, hv.z, hv.w};
        unsigned gu[4] = {gv.x, gv.y, gv.z, gv.w};
        #pragma unroll
        for (int q = 0; q < 4; ++q) {
            __half2 h2 = *(const __half2*)&hu[q];
            __half2 g2 = *(const __half2*)&gu[q];
            #pragma unroll
            for (int e = 0; e < 2; ++e) {
                const int i = j4 * 8 + q * 2 + e;
                float hf = (e ? __high2float(h2) : __low2float(h2)) + bh;
                float gf = (e ? __high2float(g2) : __low2float(g2)) + bg;
                float ex  = __expf(gf);
                float inv = 1.f / (1.f + ex);
                float ci  = inv;        // sigmoid(-gate)
                float zi  = ex * inv;   // sigmoid(gate)
                float gv2 = (hf >= 0.f) ? (1.f + hf) : __expf(hf);
                float vi  = zi * gv2;
                c[i] = ci; v[i] = vi;
                Bv = ci * Bv + vi;
                A *= ci;
            }
        }
    }

    sA[t] = A; sB[t] = Bv;
    __syncthreads();
    for (int off = 1; off < 256; off <<= 1) {
        float pA = 1.f, pB = 0.f;
        if (t >= off) { pA = sA[t - off]; pB = sB[t - off]; }
        __syncthreads();
        Bv = Bv + A * pB;
        A  = A * pA;
        sA[t] = A; sB[t] = Bv;
        __syncthreads();
    }
    float hr = (t > 0) ? sB[t - 1] : 0.f;

    // write outputs into LDS (chunk stride 36 floats), then coalesced store
    float* sO = (float*)sBuf;   // safe: all sH/sG reads are behind barriers
    #pragma unroll
    for (int i = 0; i < 32; i += 4) {
        float4 o4;
        o4.x = hr = c[i + 0] * hr + v[i + 0];
        o4.y = hr = c[i + 1] * hr + v[i + 1];
        o4.z = hr = c[i + 2] * hr + v[i + 2];
        o4.w = hr = c[i + 3] * hr + v[i + 3];
        *(float4*)&sO[t * 36 + i] = o4;
    }
    __syncthreads();

    float4* op4 = (float4*)(out + ((size_t)b * H_ + k) * L_);
    #pragma unroll
    for (int j = 0; j < 8; ++j) {
        int idx = t + 256 * j;               // float4 index 0..2047
        int cc = idx >> 3, ss = idx & 7;     // chunk 32 floats, pad to 36
        op4[idx] = *(const float4*)&sO[cc * 36 + ss * 4];
    }
}

// ---------------- fallback: fully fused naive (if ws too small) -------------
__global__ __launch_bounds__(256) void fused_naive(const float* __restrict__ x,
                                                   const float* __restrict__ W,
                                                   const float* __restrict__ bias,
                                                   float* __restrict__ out) {
    __shared__ float Wh[512];
    __shared__ float Wg[512];
    __shared__ float sA[256];
    __shared__ float sB[256];
    const int bid = blockIdx.x;
    const int b = bid >> 9;
    const int k = bid & 511;
    const int t = threadIdx.x;

    for (int i = t; i < 512; i += 256) {
        Wh[i] = W[(size_t)k * D_ + i];
        Wg[i] = W[(size_t)(H_ + k) * D_ + i];
    }
    const float bh = bias[k];
    const float bg = bias[H_ + k];
    __syncthreads();

    float Hc = 0.f;
    const float* xb = x + (size_t)b * D_ * L_;
    for (int ch = 0; ch < 32; ++ch) {
        const int l = ch * 256 + t;
        float ah = bh, ag = bg;
        for (int d = 0; d < 512; ++d) {
            float xv = xb[(size_t)d * L_ + l];
            ah += Wh[d] * xv;
            ag += Wg[d] * xv;
        }
        float e   = __expf(ag);
        float inv = 1.f / (1.f + e);
        float ci  = inv;
        float zi  = e * inv;
        float gv  = (ah >= 0.f) ? (1.f + ah) : __expf(ah);
        float vi  = zi * gv;

        float A = ci, Bv = vi;
        sA[t] = A; sB[t] = Bv;
        __syncthreads();
        for (int off = 1; off < 256; off <<= 1) {
            float pA = 1.f, pB = 0.f;
            if (t >= off) { pA = sA[t - off]; pB = sB[t - off]; }
            __syncthreads();
            Bv = Bv + A * pB;
            A  = A * pA;
            sA[t] = A; sB[t] = Bv;
            __syncthreads();
        }
        out[((size_t)b * H_ + k) * L_ + l] = A * Hc + Bv;
        float An = sA[255], Bn = sB[255];
        Hc = An * Hc + Bn;
        __syncthreads();
    }
}

extern "C" void kernel_launch(void* const* d_in, const int* in_sizes, int n_in,
                              void* d_out, int out_size, void* d_ws, size_t ws_size,
                              hipStream_t stream) {
    const float* x    = (const float*)d_in[0];
    const float* W    = (const float*)d_in[1];
    const float* bias = (const float*)d_in[2];
    float* out = (float*)d_out;

    const size_t xT_bytes = (size_t)B_ * L_ * D_ * 2;        //  67,108,864
    const size_t Wr_bytes = (size_t)O2_ * D_ * 2;            //   1,048,576
    const size_t hg_bytes = (size_t)B_ * O2_ * L_ * 2;       // 134,217,728
    const size_t need = xT_bytes + Wr_bytes + hg_bytes;      // ~202 MB

    if (ws_size >= need) {
        char* ws = (char*)d_ws;
        unsigned short* xT = (unsigned short*)ws;
        unsigned short* Wr = (unsigned short*)(ws + xT_bytes);
        __half*         hg = (__half*)(ws + xT_bytes + Wr_bytes);

        prep_w<<<512, 256, 0, stream>>>(W, Wr);
        transpose_x<<<dim3(L_ / 64, D_ / 64, B_), 256, 0, stream>>>(x, xT);
        gemm_hg<<<dim3(L_ / 128, O2_ / 128, B_), 256, 0, stream>>>(Wr, xT, hg);
        scan_seq<<<B_ * H_, 256, 0, stream>>>(hg, bias, out);
    } else {
        fused_naive<<<B_ * H_, 256, 0, stream>>>(x, W, bias, out);
    }
}

// Round 3
// 345.204 us; speedup vs baseline: 1.0658x; 1.0495x over previous
//
#include <hip/hip_runtime.h>
#include <hip/hip_fp16.h>

#define B_  8
#define D_  512
#define H_  512
#define L_  8192
#define O2_ 1024   // 2*H

typedef __attribute__((ext_vector_type(8))) short   bf16x8;
typedef __attribute__((ext_vector_type(4))) float   floatx4;
typedef __attribute__((ext_vector_type(8))) unsigned short ushort8_t;
typedef __attribute__((ext_vector_type(4))) unsigned short ushort4_t;

__device__ __forceinline__ unsigned short f2bf(float f) {
    union { float f; unsigned u; } x; x.f = f;
    unsigned u = x.u;
    u += 0x7FFFu + ((u >> 16) & 1u);   // round-to-nearest-even
    return (unsigned short)(u >> 16);
}

// async global->LDS, 16B per lane; LDS dest = wave-uniform base + lane*16
__device__ __forceinline__ void async_load16(const void* g, void* l) {
    __builtin_amdgcn_global_load_lds(
        (const __attribute__((address_space(1))) unsigned int*)g,
        (__attribute__((address_space(3))) unsigned int*)l,
        16, 0, 0);
}

// ---------------- K0: reorder W rows (pair-interleave) + convert to bf16 ----
__global__ __launch_bounds__(256) void prep_w(const float* __restrict__ W,
                                              unsigned short* __restrict__ Wr) {
    int idx  = blockIdx.x * 256 + threadIdx.x;
    int flat = idx * 4;
    int o = flat >> 9;        // /512
    int d = flat & 511;
    int src_o = (o & 1) ? (H_ + (o >> 1)) : (o >> 1);
    float4 wv = *(const float4*)(W + (size_t)src_o * D_ + d);
    ushort4_t r;
    r.x = f2bf(wv.x); r.y = f2bf(wv.y); r.z = f2bf(wv.z); r.w = f2bf(wv.w);
    *(ushort4_t*)(Wr + (size_t)o * D_ + d) = r;
}

// ---------------- K1: x [B][D][L] fp32  ->  xT [B][L][D] bf16 ---------------
__global__ __launch_bounds__(256) void transpose_x(const float* __restrict__ x,
                                                   unsigned short* __restrict__ xT) {
    __shared__ float T[64][65];
    const int b  = blockIdx.z;
    const int d0 = blockIdx.y * 64;
    const int l0 = blockIdx.x * 64;
    const int tid = threadIdx.x;

    const int c  = tid & 15;       // float4 column within l
    const int r0 = tid >> 4;       // starting d-row
    const float* xp = x + ((size_t)b * D_ + d0) * L_ + l0;
    for (int rr = r0; rr < 64; rr += 16) {
        float4 vv = *(const float4*)(xp + (size_t)rr * L_ + c * 4);
        T[c * 4 + 0][rr] = vv.x;
        T[c * 4 + 1][rr] = vv.y;
        T[c * 4 + 2][rr] = vv.z;
        T[c * 4 + 3][rr] = vv.w;
    }
    __syncthreads();

    const int dc  = (tid & 7) * 8;  // d chunk (8 bf16 = 16B store)
    const int lr0 = tid >> 3;       // l row
    unsigned short* op = xT + ((size_t)b * L_ + l0) * D_ + d0;
    for (int lr = lr0; lr < 64; lr += 32) {
        ushort8_t o8;
        o8[0] = f2bf(T[lr][dc + 0]); o8[1] = f2bf(T[lr][dc + 1]);
        o8[2] = f2bf(T[lr][dc + 2]); o8[3] = f2bf(T[lr][dc + 3]);
        o8[4] = f2bf(T[lr][dc + 4]); o8[5] = f2bf(T[lr][dc + 5]);
        o8[6] = f2bf(T[lr][dc + 6]); o8[7] = f2bf(T[lr][dc + 7]);
        *(ushort8_t*)(op + (size_t)lr * D_ + dc) = o8;
    }
}

// ---------------- K2: hg = Wr @ xT^T  (global_load_lds + XOR swizzle) -------
// Physical LDS slot (row r, 16B-chunk cs) holds logical chunk cs^(r&7).
// Staging: lane i sources global chunk (i&7)^(i>>3) so the DMA's fixed
// dest (base+lane*16) lands data in the swizzled slot. Fragment reads use
// pc = lc ^ (r&7) -> quads spread over all 8 bank groups (2-way = free).
__global__ __launch_bounds__(256) void gemm_hg(const unsigned short* __restrict__ Wr,
                                               const unsigned short* __restrict__ xT,
                                               __half* __restrict__ hg) {
    __shared__ __align__(16) unsigned short As[128][64];   // 16 KB
    __shared__ __align__(16) unsigned short Bs[128][64];   // 16 KB

    const int b  = blockIdx.z;
    const int o0 = blockIdx.y * 128;
    const int l0 = blockIdx.x * 128;
    const int tid  = threadIdx.x;
    const int lane = tid & 63;
    const int w    = tid >> 6;
    const int wm   = (w >> 1) * 64;
    const int wn   = (w & 1) * 64;
    const int lm   = lane & 15;
    const int quad = lane >> 4;

    floatx4 acc[4][4];
    for (int mi = 0; mi < 4; ++mi)
        for (int ni = 0; ni < 4; ++ni)
            acc[mi][ni] = (floatx4){0.f, 0.f, 0.f, 0.f};

    // staging source: lane i -> row j=i>>3 within the 8-row group,
    // global chunk cg = (i&7) ^ j  (XOR swizzle via source permutation)
    const int sj  = lane >> 3;
    const int scg = (lane & 7) ^ sj;
    const unsigned short* Ag = Wr + (size_t)(o0 + w * 32 + sj) * D_ + scg * 8;
    const unsigned short* Bg = xT + ((size_t)b * L_ + l0 + w * 32 + sj) * D_ + scg * 8;

    for (int kk = 0; kk < 8; ++kk) {
        const int k0 = kk * 64;
        #pragma unroll
        for (int p = 0; p < 4; ++p) {
            async_load16(Ag + (size_t)(p * 8) * D_ + k0, &As[w * 32 + p * 8][0]);
            async_load16(Bg + (size_t)(p * 8) * D_ + k0, &Bs[w * 32 + p * 8][0]);
        }
        __syncthreads();   // drains vmcnt -> LDS visible

        #pragma unroll
        for (int ks = 0; ks < 2; ++ks) {
            const int lc = ks * 4 + quad;      // logical 16B chunk (=koff/8)
            bf16x8 af[4], bfv[4];
            #pragma unroll
            for (int mi = 0; mi < 4; ++mi) {
                const int r = wm + mi * 16 + lm;
                af[mi] = *(const bf16x8*)&As[r][(lc ^ (r & 7)) * 8];
            }
            #pragma unroll
            for (int ni = 0; ni < 4; ++ni) {
                const int r = wn + ni * 16 + lm;
                bfv[ni] = *(const bf16x8*)&Bs[r][(lc ^ (r & 7)) * 8];
            }
            #pragma unroll
            for (int mi = 0; mi < 4; ++mi)
                #pragma unroll
                for (int ni = 0; ni < 4; ++ni)
                    acc[mi][ni] = __builtin_amdgcn_mfma_f32_16x16x32_bf16(
                        af[mi], bfv[ni], acc[mi][ni], 0, 0, 0);
        }
        __syncthreads();
    }

    // epilogue: D[row=quad*4+r][col=lm] per 16x16 tile
    __half* hp = hg + ((size_t)b * O2_ + o0 + wm + quad * 4) * L_ + l0 + wn + lm;
    for (int mi = 0; mi < 4; ++mi)
        for (int ni = 0; ni < 4; ++ni)
            for (int r = 0; r < 4; ++r)
                hp[(size_t)(mi * 16 + r) * L_ + ni * 16] = __float2half(acc[mi][ni][r]);
}

// ---------------- K3: per-(b,k) chunked scan — shfl wave scan, 3 barriers ---
__global__ __launch_bounds__(256) void scan_seq(const __half* __restrict__ hg,
                                                const float* __restrict__ bias,
                                                float* __restrict__ out) {
    // sBuf: h chunks [256][20] uints + g chunks [256][20]; reused as
    // out chunks [256][36] floats after the scan.
    __shared__ __align__(16) unsigned int sBuf[256 * 40];
    __shared__ float wA[4];
    __shared__ float wB[4];
    unsigned int* sH = sBuf;
    unsigned int* sG = sBuf + 256 * 20;

    const int bid = blockIdx.x;
    const int b = bid >> 9;
    const int k = bid & 511;
    const int t = threadIdx.x;
    const int lane = t & 63;
    const int wid  = t >> 6;

    const uint4* hq = (const uint4*)(hg + ((size_t)b * O2_ + 2 * k) * L_);
    const uint4* gq = hq + (L_ / 8);   // next row (gate)

    #pragma unroll
    for (int j = 0; j < 4; ++j) {
        int idx = t + 256 * j;               // uint4 index 0..1023
        uint4 hv = hq[idx];
        uint4 gv = gq[idx];
        int cc = idx >> 2, ss = idx & 3;     // chunk 16 uints, pad to 20
        *(uint4*)&sH[cc * 20 + ss * 4] = hv;
        *(uint4*)&sG[cc * 20 + ss * 4] = gv;
    }
    const float bh = bias[k];
    const float bg = bias[H_ + k];
    __syncthreads();                                           // barrier 1

    float c[32], v[32];
    float A = 1.f, Bv = 0.f;
    #pragma unroll
    for (int j4 = 0; j4 < 4; ++j4) {
        uint4 hv = *(const uint4*)&sH[t * 20 + j4 * 4];
        uint4 gv = *(const uint4*)&sG[t * 20 + j4 * 4];
        unsigned hu[4] = {hv.x, hv.y, hv.z, hv.w};
        unsigned gu[4] = {gv.x, gv.y, gv.z, gv.w};
        #pragma unroll
        for (int q = 0; q < 4; ++q) {
            __half2 h2 = *(const __half2*)&hu[q];
            __half2 g2 = *(const __half2*)&gu[q];
            #pragma unroll
            for (int e = 0; e < 2; ++e) {
                const int i = j4 * 8 + q * 2 + e;
                float hf = (e ? __high2float(h2) : __low2float(h2)) + bh;
                float gf = (e ? __high2float(g2) : __low2float(g2)) + bg;
                float ex  = __expf(gf);
                float inv = 1.f / (1.f + ex);
                float ci  = inv;        // sigmoid(-gate)
                float zi  = ex * inv;   // sigmoid(gate)
                float gv2 = (hf >= 0.f) ? (1.f + hf) : __expf(hf);
                float vi  = zi * gv2;
                c[i] = ci; v[i] = vi;
                Bv = ci * Bv + vi;
                A *= ci;
            }
        }
    }

    // wave-level inclusive scan of (A,B) composition, no barriers
    #pragma unroll
    for (int off = 1; off < 64; off <<= 1) {
        float pA = __shfl_up(A, off);
        float pB = __shfl_up(Bv, off);
        if (lane >= off) { Bv = Bv + A * pB; A = A * pA; }
    }

    if (lane == 63) { wA[wid] = A; wB[wid] = Bv; }
    __syncthreads();                                           // barrier 2

    // carry from preceding waves (composed in order)
    float cB = 0.f;
    for (int p = 0; p < wid; ++p) cB = wB[p] + wA[p] * cB;

    // exclusive lane prefix within wave
    float eA = __shfl_up(A, 1);
    float eB = __shfl_up(Bv, 1);
    if (lane == 0) { eA = 1.f; eB = 0.f; }
    float hr = eB + eA * cB;   // H entering this thread's chunk (H0 = 0)

    // outputs into LDS (chunk stride 36 floats), then coalesced store.
    // sBuf reuse safe: all sH/sG reads happened before barrier 2.
    float* sO = (float*)sBuf;
    #pragma unroll
    for (int i = 0; i < 32; i += 4) {
        float4 o4;
        o4.x = hr = c[i + 0] * hr + v[i + 0];
        o4.y = hr = c[i + 1] * hr + v[i + 1];
        o4.z = hr = c[i + 2] * hr + v[i + 2];
        o4.w = hr = c[i + 3] * hr + v[i + 3];
        *(float4*)&sO[t * 36 + i] = o4;
    }
    __syncthreads();                                           // barrier 3

    float4* op4 = (float4*)(out + ((size_t)b * H_ + k) * L_);
    #pragma unroll
    for (int j = 0; j < 8; ++j) {
        int idx = t + 256 * j;               // float4 index 0..2047
        int cc = idx >> 3, ss = idx & 7;     // chunk 32 floats, pad to 36
        op4[idx] = *(const float4*)&sO[cc * 36 + ss * 4];
    }
}

// ---------------- fallback: fully fused naive (if ws too small) -------------
__global__ __launch_bounds__(256) void fused_naive(const float* __restrict__ x,
                                                   const float* __restrict__ W,
                                                   const float* __restrict__ bias,
                                                   float* __restrict__ out) {
    __shared__ float Wh[512];
    __shared__ float Wg[512];
    __shared__ float sA[256];
    __shared__ float sB[256];
    const int bid = blockIdx.x;
    const int b = bid >> 9;
    const int k = bid & 511;
    const int t = threadIdx.x;

    for (int i = t; i < 512; i += 256) {
        Wh[i] = W[(size_t)k * D_ + i];
        Wg[i] = W[(size_t)(H_ + k) * D_ + i];
    }
    const float bh = bias[k];
    const float bg = bias[H_ + k];
    __syncthreads();

    float Hc = 0.f;
    const float* xb = x + (size_t)b * D_ * L_;
    for (int ch = 0; ch < 32; ++ch) {
        const int l = ch * 256 + t;
        float ah = bh, ag = bg;
        for (int d = 0; d < 512; ++d) {
            float xv = xb[(size_t)d * L_ + l];
            ah += Wh[d] * xv;
            ag += Wg[d] * xv;
        }
        float e   = __expf(ag);
        float inv = 1.f / (1.f + e);
        float ci  = inv;
        float zi  = e * inv;
        float gv  = (ah >= 0.f) ? (1.f + ah) : __expf(ah);
        float vi  = zi * gv;

        float A = ci, Bv = vi;
        sA[t] = A; sB[t] = Bv;
        __syncthreads();
        for (int off = 1; off < 256; off <<= 1) {
            float pA = 1.f, pB = 0.f;
            if (t >= off) { pA = sA[t - off]; pB = sB[t - off]; }
            __syncthreads();
            Bv = Bv + A * pB;
            A  = A * pA;
            sA[t] = A; sB[t] = Bv;
            __syncthreads();
        }
        out[((size_t)b * H_ + k) * L_ + l] = A * Hc + Bv;
        float An = sA[255], Bn = sB[255];
        Hc = An * Hc + Bn;
        __syncthreads();
    }
}

extern "C" void kernel_launch(void* const* d_in, const int* in_sizes, int n_in,
                              void* d_out, int out_size, void* d_ws, size_t ws_size,
                              hipStream_t stream) {
    const float* x    = (const float*)d_in[0];
    const float* W    = (const float*)d_in[1];
    const float* bias = (const float*)d_in[2];
    float* out = (float*)d_out;

    const size_t xT_bytes = (size_t)B_ * L_ * D_ * 2;        //  67,108,864
    const size_t Wr_bytes = (size_t)O2_ * D_ * 2;            //   1,048,576
    const size_t hg_bytes = (size_t)B_ * O2_ * L_ * 2;       // 134,217,728
    const size_t need = xT_bytes + Wr_bytes + hg_bytes;      // ~202 MB

    if (ws_size >= need) {
        char* ws = (char*)d_ws;
        unsigned short* xT = (unsigned short*)ws;
        unsigned short* Wr = (unsigned short*)(ws + xT_bytes);
        __half*         hg = (__half*)(ws + xT_bytes + Wr_bytes);

        prep_w<<<512, 256, 0, stream>>>(W, Wr);
        transpose_x<<<dim3(L_ / 64, D_ / 64, B_), 256, 0, stream>>>(x, xT);
        gemm_hg<<<dim3(L_ / 128, O2_ / 128, B_), 256, 0, stream>>>(Wr, xT, hg);
        scan_seq<<<B_ * H_, 256, 0, stream>>>(hg, bias, out);
    } else {
        fused_naive<<<B_ * H_, 256, 0, stream>>>(x, W, bias, out);
    }
}